// Round 11
// baseline (296.786 us; speedup 1.0000x reference)
//
#include <hip/hip_runtime.h>

typedef __bf16 bf16;
typedef __attribute__((ext_vector_type(8))) __bf16 bf16x8;
typedef __attribute__((ext_vector_type(4))) __bf16 bf16x4;
typedef __attribute__((ext_vector_type(4))) float f32x4;

#define GLDS16(g, l) __builtin_amdgcn_global_load_lds( \
    (const __attribute__((address_space(1))) void*)(g), \
    (__attribute__((address_space(3))) void*)(l), 16, 0, 0)

#define MFMA16(a, b, c) __builtin_amdgcn_mfma_f32_16x16x32_bf16(a, b, c, 0, 0, 0)

// ds_read_b64_tr_b16: per-lane gather of 4 bf16 at 32B stride (HW transpose read)
#define TR16(dst, addr, off) \
  asm volatile("ds_read_b64_tr_b16 %0, %1 offset:" #off : "=v"(dst) : "v"(addr))

// ---------------------------------------------------------------- convert (all 7 tensors, 1 dispatch)
struct CvtAll { const float* in[7]; bf16* out[7]; };

__global__ __launch_bounds__(256) void f2b_all(CvtAll a) {
  const int i = blockIdx.x * 256 + threadIdx.x;
  const float* in;
  bf16* out;
  int off;
  if (blockIdx.y < 3) {            // Q, K, V: 1048576 8-chunks each
    in = a.in[blockIdx.y];
    out = a.out[blockIdx.y];
    off = i;
  } else {                          // 4 weights: 131072 8-chunks each
    if (i >= 524288) return;
    const int widx = 3 + (i >> 17);
    in = a.in[widx];
    out = a.out[widx];
    off = i & 131071;
  }
  const f32x4* p = (const f32x4*)in + (size_t)off * 2;
  f32x4 x = p[0], y = p[1];
  bf16x8 o;
  o[0] = (bf16)x[0]; o[1] = (bf16)x[1]; o[2] = (bf16)x[2]; o[3] = (bf16)x[3];
  o[4] = (bf16)y[0]; o[5] = (bf16)y[1]; o[6] = (bf16)y[2]; o[7] = (bf16)y[3];
  ((bf16x8*)out)[off] = o;
}

// ---------------------------------------------------------------- GEMM 8-phase (hardened barriers)
// C[m,n] = sum_k A[m,k] * Bw[n,k]  (+bias[n])
// 256x256 / BK=64 / 8 waves (2Mx4N, per-wave 128x64) / 8-phase counted-vmcnt.
// HARDENING vs R9/R10: the phase-ending barrier (ENDP) gates freshly staged
// LDS data whose arrival is guaranteed by OTHER waves' vmcnt waits. A bare
// s_barrier intrinsic is NOT a compiler memory barrier, so the next phase's
// plain-pointer ds_reads could be hoisted above it (reading a slice another
// wave hasn't finished staging -> flaky race, R10's post-timing divergence).
// ENDP now adds an empty asm memory clobber + sched_barrier(0): zero runtime
// cost, forbids the hoist. Same at the prologue barrier.
template <int EPI>
__device__ __forceinline__ void gemm_body8(
    const bf16* __restrict__ A, const bf16* __restrict__ Bw,
    const float* __restrict__ bias, const float* __restrict__ qv,
    bf16* __restrict__ C, float* __restrict__ part,
    const int row0, const int col0, const int N, const int K) {
  __shared__ __attribute__((aligned(16))) bf16 L[2][4][8192];  // 128 KB
  const int tid = threadIdx.x;
  const int wid = tid >> 6, lane = tid & 63;
  const int g = lane >> 4, lc = lane & 15;
  const int wr = wid >> 2, wc = wid & 3;  // 2 row-slabs x 4 col-slabs

  const bf16* gA = A + (size_t)(row0 + (tid & 255)) * K + (tid >> 8) * 8;
  const bf16* gB = Bw + (size_t)(col0 + (tid & 255)) * K + (tid >> 8) * 8;
  const int d0 = (tid - lane) * 8;  // wave-uniform LDS dest (elements)

#define STG_A(T, kh) do { \
    const bf16* gp_ = gA + (T) * 64 + (kh) * 32; \
    bf16* lp_ = &L[(T) & 1][(kh)][d0]; \
    GLDS16(gp_, lp_); GLDS16(gp_ + 16, lp_ + 4096); } while (0)
#define STG_B(T, kh) do { \
    const bf16* gp_ = gB + (T) * 64 + (kh) * 32; \
    bf16* lp_ = &L[(T) & 1][2 + (kh)][d0]; \
    GLDS16(gp_, lp_); GLDS16(gp_ + 16, lp_ + 4096); } while (0)
#define RD_A(c, kh) do { \
    _Pragma("unroll") for (int m_ = 0; m_ < 8; ++m_) \
      af[m_] = *(const bf16x8*)&L[c][kh][(g * 256 + wr * 128 + m_ * 16 + lc) * 8]; \
  } while (0)
#define RD_B(c, kh, nh) do { \
    bf[0] = *(const bf16x8*)&L[c][2 + (kh)][(g * 256 + wc * 64 + (nh) * 32 + lc) * 8]; \
    bf[1] = *(const bf16x8*)&L[c][2 + (kh)][(g * 256 + wc * 64 + (nh) * 32 + 16 + lc) * 8]; \
  } while (0)
#define BARS \
    __builtin_amdgcn_s_barrier(); \
    asm volatile("s_waitcnt lgkmcnt(0)" ::: "memory"); \
    __builtin_amdgcn_sched_barrier(0);
#define MM(nh) do { \
    __builtin_amdgcn_s_setprio(1); \
    _Pragma("unroll") for (int m_ = 0; m_ < 8; ++m_) { \
      acc[m_][(nh) * 2 + 0] = MFMA16(af[m_], bf[0], acc[m_][(nh) * 2 + 0]); \
      acc[m_][(nh) * 2 + 1] = MFMA16(af[m_], bf[1], acc[m_][(nh) * 2 + 1]); \
    } \
    __builtin_amdgcn_s_setprio(0); } while (0)
// Hardened phase-end barrier: also a compiler memory fence + sched fence so
// the next phase's ds_reads cannot be hoisted above the wave-sync point.
#define ENDP do { \
    __builtin_amdgcn_s_barrier(); \
    asm volatile("" ::: "memory"); \
    __builtin_amdgcn_sched_barrier(0); } while (0)

  const f32x4 z4 = {0.f, 0.f, 0.f, 0.f};
  f32x4 acc[8][4];
#pragma unroll
  for (int m = 0; m < 8; ++m)
#pragma unroll
    for (int n = 0; n < 4; ++n) acc[m][n] = z4;

  bf16x8 af[8], bf[2];
  const int NT = K >> 6;   // K-tiles of 64
  const int NI = NT >> 1;  // iterations (2 tiles each)

  // prologue: tile0 complete + tile1 {A_k0, B_k0, A_k1} = 7 half-tiles
  STG_A(0, 0); STG_B(0, 0); STG_A(0, 1); STG_B(0, 1);
  STG_A(1, 0); STG_B(1, 0); STG_A(1, 1);
  asm volatile("s_waitcnt vmcnt(6)" ::: "memory");  // oldest 8 = tile0 landed
  ENDP;  // hardened: P1's reads must not hoist above this barrier

  for (int i = 0; i < NI; ++i) {
    const int t1 = 2 * i + 1, t2 = 2 * i + 2, t3 = 2 * i + 3;
    const bool p2 = t2 < NT, p3 = t3 < NT;
    // phase 1 (buf0, kh0, nh0)
    RD_A(0, 0); RD_B(0, 0, 0);
    STG_B(t1, 1);
    BARS; MM(0); ENDP;
    // phase 2 (kh0, nh1)
    RD_B(0, 0, 1);
    if (p2) STG_A(t2, 0);
    BARS; MM(1); ENDP;
    // phase 3 (kh1, nh0)
    RD_A(0, 1); RD_B(0, 1, 0);
    if (p2) STG_B(t2, 0);
    BARS; MM(0); ENDP;
    // phase 4 (kh1, nh1) + fence gating buf1 consumption
    RD_B(0, 1, 1);
    if (p2) STG_A(t2, 1);
    BARS; MM(1);
    if (p2) { asm volatile("s_waitcnt vmcnt(6)" ::: "memory"); }
    else    { asm volatile("s_waitcnt vmcnt(0)" ::: "memory"); }
    ENDP;
    // phase 5 (buf1, kh0, nh0)
    RD_A(1, 0); RD_B(1, 0, 0);
    if (p2) STG_B(t2, 1);
    BARS; MM(0); ENDP;
    // phase 6 (kh0, nh1)
    RD_B(1, 0, 1);
    if (p3) STG_A(t3, 0);
    BARS; MM(1); ENDP;
    // phase 7 (kh1, nh0)
    RD_A(1, 1); RD_B(1, 1, 0);
    if (p3) STG_B(t3, 0);
    BARS; MM(0); ENDP;
    // phase 8 (kh1, nh1) + fence gating next-iter buf0 consumption
    RD_B(1, 1, 1);
    if (p3) STG_A(t3, 1);
    BARS; MM(1);
    asm volatile("s_waitcnt vmcnt(6)" ::: "memory");  // trivial on last iter
    ENDP;
  }

#undef STG_A
#undef STG_B
#undef RD_A
#undef RD_B
#undef BARS
#undef MM
#undef ENDP

  if constexpr (EPI == 0) {
#pragma unroll
    for (int n = 0; n < 4; ++n) {
      const int col = col0 + wc * 64 + n * 16 + lc;
      const float bb = bias[col];
#pragma unroll
      for (int m = 0; m < 8; ++m)
#pragma unroll
        for (int r = 0; r < 4; ++r) {
          const int row = row0 + wr * 128 + m * 16 + g * 4 + r;
          C[(size_t)row * N + col] = (bf16)(acc[m][n][r] + bb);
        }
    }
  } else {
    float ps[8][4];
#pragma unroll
    for (int m = 0; m < 8; ++m)
#pragma unroll
      for (int r = 0; r < 4; ++r) ps[m][r] = 0.f;
#pragma unroll
    for (int n = 0; n < 4; ++n) {
      const int col = col0 + wc * 64 + n * 16 + lc;
      const float bb = bias[col];
      const float qq = qv[col];
#pragma unroll
      for (int m = 0; m < 8; ++m)
#pragma unroll
        for (int r = 0; r < 4; ++r)
          ps[m][r] += tanhf(acc[m][n][r] + bb) * qq;
    }
    // plain partial store per 64-col slab: slab = (col0>>8)*4 + wc in [0,16)
    float* pdst = part + (size_t)((col0 >> 8) * 4 + wc) * 8192;
#pragma unroll
    for (int m = 0; m < 8; ++m)
#pragma unroll
      for (int r = 0; r < 4; ++r) {
        float v = ps[m][r];
        v += __shfl_xor(v, 1); v += __shfl_xor(v, 2);
        v += __shfl_xor(v, 4); v += __shfl_xor(v, 8);
        if (lc == 0) {
          const int row = row0 + wr * 128 + m * 16 + g * 4 + r;
          pdst[row] = v;
        }
      }
  }
}

// Swizzle for 128 blocks/GEMM (32 row-tiles x 4 col-tiles, 256^2):
// phys p -> lg = (p&7)*16 + (p>>3); XCD k gets rows [4k,4k+4) x all 4 cols.
__device__ __forceinline__ void swz128(int phys, int& row0, int& col0) {
  const int lg = (phys & 7) * 16 + (phys >> 3);
  row0 = (lg >> 2) * 256;
  col0 = (lg & 3) * 256;
}

struct GemmSet { const bf16* A; const bf16* Bw; const float* bias; bf16* C; };
struct Gemm3Args { GemmSet s[3]; };

__global__ __launch_bounds__(512, 2) void gemm3_kernel(Gemm3Args a) {
  const GemmSet s = a.s[blockIdx.y];
  int row0, col0;
  swz128(blockIdx.x, row0, col0);
  gemm_body8<0>(s.A, s.Bw, s.bias, nullptr, s.C, nullptr, row0, col0, 1024, 1024);
}

__global__ __launch_bounds__(512, 2) void gemm_a_kernel(
    const bf16* __restrict__ A, const bf16* __restrict__ Bw,
    const float* __restrict__ bias, const float* __restrict__ qv,
    float* __restrict__ part) {
  int row0, col0;
  swz128(blockIdx.x, row0, col0);
  gemm_body8<1>(A, Bw, bias, qv, nullptr, part, row0, col0, 1024, 1024);
}

// ---------------------------------------------------------------- attention (validated R4-R9 form)
__global__ __launch_bounds__(256) void attn_kernel(
    const bf16* __restrict__ qp, const bf16* __restrict__ kp,
    const bf16* __restrict__ vp, bf16* __restrict__ xb, float* __restrict__ xf) {
  constexpr int S = 1024, D = 1024;
  __shared__ __attribute__((aligned(16))) bf16 Ks[8192];  // 2x [d/8][64 kv][8]
  __shared__ __attribute__((aligned(16))) bf16 Vs[8192];  // 2x [kv/4][d/16][4][16]
  __shared__ __attribute__((aligned(16))) bf16 Ps[4096];  // per-wave [16 q][64 kv swz]
  const int tid = threadIdx.x, wid = tid >> 6, lane = tid & 63;
  const int g = lane >> 4, lc = lane & 15;
  const int b = blockIdx.x >> 4, h = blockIdx.x & 15;
  const int q0 = blockIdx.y * 64;
  const size_t base = (size_t)b * S * D + (size_t)h * 64;

  bf16x8 qf[2];
  {
    const bf16* qrow = qp + base + (size_t)(q0 + wid * 16 + lc) * D;
    qf[0] = *(const bf16x8*)(qrow + g * 8);
    qf[1] = *(const bf16x8*)(qrow + 32 + g * 8);
#pragma unroll
    for (int j = 0; j < 8; ++j) {
      qf[0][j] = (bf16)((float)qf[0][j] * 0.125f);
      qf[1][j] = (bf16)((float)qf[1][j] * 0.125f);
    }
  }
  float m_s = -1e30f, l_s = 0.f;
  const f32x4 z4 = {0.f, 0.f, 0.f, 0.f};
  f32x4 ax[4];
#pragma unroll
  for (int m = 0; m < 4; ++m) ax[m] = z4;

  const int c0 = tid, c1 = tid + 256;
  const bf16* gK0 = kp + base + (size_t)(c0 & 63) * D + (c0 >> 6) * 8;
  const bf16* gK1 = kp + base + (size_t)(c1 & 63) * D + (c1 >> 6) * 8;
  bf16* lK0 = Ks + (size_t)(c0 - lane) * 8;
  bf16* lK1 = Ks + (size_t)(c1 - lane) * 8;
  const bf16* gV0 = vp + base + (size_t)((c0 >> 5) * 4 + ((c0 >> 1) & 3)) * D +
                    ((c0 >> 3) & 3) * 16 + (c0 & 1) * 8;
  const bf16* gV1 = vp + base + (size_t)((c1 >> 5) * 4 + ((c1 >> 1) & 3)) * D +
                    ((c1 >> 3) & 3) * 16 + (c1 & 1) * 8;
  bf16* lV0 = Vs + (size_t)(c0 - lane) * 8;
  bf16* lV1 = Vs + (size_t)(c1 - lane) * 8;

  bf16* pw = Ps + wid * 1024;
  const int pswz_a = lc & 3, pswz_b = (lc >> 2) & 3;
  const unsigned vaddr0 =
      (unsigned)(uintptr_t)(const __attribute__((address_space(3))) bf16*)(Vs + 512 * g + 4 * lc);

  GLDS16(gK0, lK0);
  GLDS16(gK1, lK1);
  GLDS16(gV0, lV0);
  GLDS16(gV1, lV1);

  for (int t = 0; t < 16; ++t) {
    __syncthreads();
    const int cur = t & 1;
    if (t < 15) {
      const size_t off = (size_t)(t + 1) * 64 * D;
      const int nb = cur ^ 1;
      GLDS16(gK0 + off, lK0 + nb * 4096);
      GLDS16(gK1 + off, lK1 + nb * 4096);
      GLDS16(gV0 + off, lV0 + nb * 4096);
      GLDS16(gV1 + off, lV1 + nb * 4096);
    }
    const bf16* Kb = Ks + cur * 4096;
    const unsigned va = vaddr0 + cur * 8192u;

    f32x4 sc[4];
    __builtin_amdgcn_s_setprio(1);
#pragma unroll
    for (int m = 0; m < 4; ++m) {
      f32x4 z = z4;
      bf16x8 kf0 = *(const bf16x8*)(Kb + (size_t)g * 512 + (m * 16 + lc) * 8);
      bf16x8 kf1 = *(const bf16x8*)(Kb + (size_t)(4 + g) * 512 + (m * 16 + lc) * 8);
      z = MFMA16(kf0, qf[0], z);
      z = MFMA16(kf1, qf[1], z);
      sc[m] = z;
    }
    __builtin_amdgcn_s_setprio(0);

    float mx = -1e30f;
#pragma unroll
    for (int m = 0; m < 4; ++m)
      mx = fmaxf(mx, fmaxf(fmaxf(sc[m][0], sc[m][1]), fmaxf(sc[m][2], sc[m][3])));
    mx = fmaxf(mx, __shfl_xor(mx, 16));
    mx = fmaxf(mx, __shfl_xor(mx, 32));
    if (!__all(mx - m_s <= 8.f)) {
      const float mn = fmaxf(m_s, mx);
      const float cr = __expf(m_s - mn);
      l_s *= cr;
#pragma unroll
      for (int m = 0; m < 4; ++m) ax[m] *= cr;
      m_s = mn;
    }
    float sm = 0.f;
#pragma unroll
    for (int m = 0; m < 4; ++m)
#pragma unroll
      for (int r = 0; r < 4; ++r) {
        float p = __expf(sc[m][r] - m_s);
        sc[m][r] = p;
        sm += p;
      }
    sm += __shfl_xor(sm, 16);
    sm += __shfl_xor(sm, 32);
    l_s += sm;

#pragma unroll
    for (int m = 0; m < 4; ++m) {
      bf16x4 pk;
      pk[0] = (bf16)sc[m][0]; pk[1] = (bf16)sc[m][1];
      pk[2] = (bf16)sc[m][2]; pk[3] = (bf16)sc[m][3];
      *(bf16x4*)(pw + lc * 64 + 16 * (m ^ pswz_a) + 4 * (g ^ pswz_b)) = pk;
    }

    bf16x4 pr[2][2];
#pragma unroll
    for (int kk = 0; kk < 2; ++kk)
#pragma unroll
      for (int jh = 0; jh < 2; ++jh) {
        const int msrc = 2 * kk + (g >> 1);
        const int gsrc = (2 * g + jh) & 3;
        pr[kk][jh] = *(const bf16x4*)(pw + lc * 64 + 16 * (msrc ^ pswz_a) + 4 * (gsrc ^ pswz_b));
      }
    bf16x8 pf0 = __builtin_shufflevector(pr[0][0], pr[0][1], 0, 1, 2, 3, 4, 5, 6, 7);
    bf16x8 pf1 = __builtin_shufflevector(pr[1][0], pr[1][1], 0, 1, 2, 3, 4, 5, 6, 7);

    bf16x4 vt[4][2][2];
    TR16(vt[0][0][0], va, 0);    TR16(vt[1][0][0], va, 128);
    TR16(vt[2][0][0], va, 256);  TR16(vt[3][0][0], va, 384);
    TR16(vt[0][0][1], va, 512);  TR16(vt[1][0][1], va, 640);
    TR16(vt[2][0][1], va, 768);  TR16(vt[3][0][1], va, 896);
    TR16(vt[0][1][0], va, 4096); TR16(vt[1][1][0], va, 4224);
    TR16(vt[2][1][0], va, 4352); TR16(vt[3][1][0], va, 4480);
    TR16(vt[0][1][1], va, 4608); TR16(vt[1][1][1], va, 4736);
    TR16(vt[2][1][1], va, 4864); TR16(vt[3][1][1], va, 4992);
    asm volatile("s_waitcnt lgkmcnt(0)" ::: "memory");
    __builtin_amdgcn_sched_barrier(0);

    __builtin_amdgcn_s_setprio(1);
#pragma unroll
    for (int md = 0; md < 4; ++md) {
      bf16x8 a0 = __builtin_shufflevector(vt[md][0][0], vt[md][0][1], 0, 1, 2, 3, 4, 5, 6, 7);
      bf16x8 a1 = __builtin_shufflevector(vt[md][1][0], vt[md][1][1], 0, 1, 2, 3, 4, 5, 6, 7);
      ax[md] = MFMA16(a0, pf0, ax[md]);
      ax[md] = MFMA16(a1, pf1, ax[md]);
    }
    __builtin_amdgcn_s_setprio(0);
  }

  const float inv = 1.0f / l_s;
  const int qrow = q0 + wid * 16 + lc;
  float* xfr = xf + base + (size_t)qrow * D;
  bf16* xbr = xb + base + (size_t)qrow * D;
#pragma unroll
  for (int m = 0; m < 4; ++m) {
    f32x4 vv = ax[m] * inv;
    *(f32x4*)(xfr + 16 * m + 4 * g) = vv;
    bf16x4 bb;
    bb[0] = (bf16)vv[0]; bb[1] = (bf16)vv[1];
    bb[2] = (bf16)vv[2]; bb[3] = (bf16)vv[3];
    *(bf16x4*)(xbr + 16 * m + 4 * g) = bb;
  }
}

// ---------------------------------------------------------------- fused alpha softmax + pooling
// 8 blocks (one per batch), 256 threads. part: [16][8192] partial tanh-dots.
__global__ __launch_bounds__(256) void alphapool_kernel(
    const float* __restrict__ part, const float* __restrict__ xf,
    float* __restrict__ out) {
  __shared__ float alpha[1024];
  __shared__ float red[8];
  const int b = blockIdx.x, t = threadIdx.x;

  // a[s] for s = t*4 .. t*4+3: sum the 16 column-slab partials
  f32x4 a4 = {0.f, 0.f, 0.f, 0.f};
#pragma unroll
  for (int p = 0; p < 16; ++p) {
    const float* pp = part + (size_t)p * 8192 + b * 1024 + t * 4;
    a4[0] += pp[0]; a4[1] += pp[1]; a4[2] += pp[2]; a4[3] += pp[3];
  }
  // block softmax over 1024 logits
  float m = fmaxf(fmaxf(a4[0], a4[1]), fmaxf(a4[2], a4[3]));
#pragma unroll
  for (int o = 1; o < 64; o <<= 1) m = fmaxf(m, __shfl_xor(m, o));
  if ((t & 63) == 0) red[t >> 6] = m;
  __syncthreads();
  m = fmaxf(fmaxf(red[0], red[1]), fmaxf(red[2], red[3]));
  f32x4 e;
  float s = 0.f;
#pragma unroll
  for (int j = 0; j < 4; ++j) { e[j] = __expf(a4[j] - m); s += e[j]; }
#pragma unroll
  for (int o = 1; o < 64; o <<= 1) s += __shfl_xor(s, o);
  if ((t & 63) == 0) red[4 + (t >> 6)] = s;
  __syncthreads();
  const float inv = 1.0f / (red[4] + red[5] + red[6] + red[7]);
  *(f32x4*)(alpha + t * 4) = e * inv;
  __syncthreads();

  // pool: out[b][d] = sum_s alpha[s] * xf[b][s][d], thread owns d = t*4..t*4+3
  f32x4 acc0 = {0.f, 0.f, 0.f, 0.f}, acc1 = {0.f, 0.f, 0.f, 0.f};
  const float* xrow = xf + (size_t)b * 1024 * 1024 + t * 4;
  for (int s2 = 0; s2 < 1024; s2 += 2) {
    acc0 += alpha[s2] * *(const f32x4*)(xrow + (size_t)s2 * 1024);
    acc1 += alpha[s2 + 1] * *(const f32x4*)(xrow + (size_t)(s2 + 1) * 1024);
  }
  *(f32x4*)(out + b * 1024 + t * 4) = acc0 + acc1;
}

// ---------------------------------------------------------------- launch
extern "C" void kernel_launch(void* const* d_in, const int* in_sizes, int n_in,
                              void* d_out, int out_size, void* d_ws, size_t ws_size,
                              hipStream_t stream) {
  const float* Q   = (const float*)d_in[0];
  const float* K   = (const float*)d_in[1];
  const float* V   = (const float*)d_in[2];
  const float* Wq  = (const float*)d_in[3];
  const float* bq  = (const float*)d_in[4];
  const float* Wk  = (const float*)d_in[5];
  const float* bk  = (const float*)d_in[6];
  const float* Wv  = (const float*)d_in[7];
  const float* bv  = (const float*)d_in[8];
  const float* Wa  = (const float*)d_in[9];
  const float* ba  = (const float*)d_in[10];
  const float* qvec = (const float*)d_in[11];
  float* out = (float*)d_out;
  char* ws = (char*)d_ws;
  const size_t MB = 1ull << 20;

  bf16* Wqb = (bf16*)(ws + 0 * MB);
  bf16* Wkb = (bf16*)(ws + 2 * MB);
  bf16* Wvb = (bf16*)(ws + 4 * MB);
  bf16* Wab = (bf16*)(ws + 6 * MB);
  bf16* qb  = (bf16*)(ws + 8 * MB);
  bf16* kb  = (bf16*)(ws + 24 * MB);
  bf16* vb  = (bf16*)(ws + 40 * MB);
  bf16* qp  = (bf16*)(ws + 56 * MB);
  bf16* kp  = (bf16*)(ws + 72 * MB);
  bf16* vp  = (bf16*)(ws + 88 * MB);
  float* part = (float*)(ws + 104 * MB);  // [16][8192] f32 = 512 KB
  bf16* xb  = qb;                       // qb dead after Q projection
  float* xf = (float*)(ws + 24 * MB);   // kb+vb dead after K/V projections

  // all f32 -> bf16 conversions in one dispatch
  CvtAll cv = {{Q, K, V, Wq, Wk, Wv, Wa}, {qb, kb, vb, Wqb, Wkb, Wvb, Wab}};
  f2b_all<<<dim3(4096, 4), 256, 0, stream>>>(cv);

  // projections: one dispatch, y = {q,k,v}; 128 swizzled 256^2 blocks per GEMM
  Gemm3Args g3 = {{{qb, Wqb, bq, qp}, {kb, Wkb, bk, kp}, {vb, Wvb, bv, vp}}};
  gemm3_kernel<<<dim3(128, 3), 512, 0, stream>>>(g3);

  // flash attention
  attn_kernel<<<dim3(128, 16), 256, 0, stream>>>(qp, kp, vp, xb, xf);

  // pooling head partials: part[slab][row] = sum_{n in slab} tanh(xWa^T+ba)*qv
  gemm_a_kernel<<<128, 512, 0, stream>>>(xb, Wab, ba, qvec, part);

  // fused alpha softmax + weighted pooling
  alphapool_kernel<<<8, 256, 0, stream>>>(part, xf, out);
}

// Round 12
// 263.222 us; speedup vs baseline: 1.1275x; 1.1275x over previous
//
#include <hip/hip_runtime.h>

typedef __bf16 bf16;
typedef __attribute__((ext_vector_type(8))) __bf16 bf16x8;
typedef __attribute__((ext_vector_type(4))) __bf16 bf16x4;
typedef __attribute__((ext_vector_type(4))) float f32x4;

#define GLDS16(g, l) __builtin_amdgcn_global_load_lds( \
    (const __attribute__((address_space(1))) void*)(g), \
    (__attribute__((address_space(3))) void*)(l), 16, 0, 0)

#define MFMA16(a, b, c) __builtin_amdgcn_mfma_f32_16x16x32_bf16(a, b, c, 0, 0, 0)

// ds_read_b64_tr_b16: per-lane gather of 4 bf16 at 32B stride (HW transpose read)
#define TR16(dst, addr, off) \
  asm volatile("ds_read_b64_tr_b16 %0, %1 offset:" #off : "=v"(dst) : "v"(addr))

// ---------------------------------------------------------------- convert (all 7 tensors, 1 dispatch)
struct CvtAll { const float* in[7]; bf16* out[7]; };

__global__ __launch_bounds__(256) void f2b_all(CvtAll a) {
  const int i = blockIdx.x * 256 + threadIdx.x;
  const float* in;
  bf16* out;
  int off;
  if (blockIdx.y < 3) {            // Q, K, V: 1048576 8-chunks each
    in = a.in[blockIdx.y];
    out = a.out[blockIdx.y];
    off = i;
  } else {                          // 4 weights: 131072 8-chunks each
    if (i >= 524288) return;
    const int widx = 3 + (i >> 17);
    in = a.in[widx];
    out = a.out[widx];
    off = i & 131071;
  }
  const f32x4* p = (const f32x4*)in + (size_t)off * 2;
  f32x4 x = p[0], y = p[1];
  bf16x8 o;
  o[0] = (bf16)x[0]; o[1] = (bf16)x[1]; o[2] = (bf16)x[2]; o[3] = (bf16)x[3];
  o[4] = (bf16)y[0]; o[5] = (bf16)y[1]; o[6] = (bf16)y[2]; o[7] = (bf16)y[3];
  ((bf16x8*)out)[off] = o;
}

// ---------------------------------------------------------------- GEMM 8-phase (hardened barriers, R11 exact)
// C[m,n] = sum_k A[m,k] * Bw[n,k]  (+bias[n])
// 256x256 / BK=64 / 8 waves (2Mx4N, per-wave 128x64) / 8-phase counted-vmcnt.
// ENDP = s_barrier + compiler memory fence + sched fence (R10's post-timing
// race was next-phase ds_reads hoisted above the bare s_barrier).
template <int EPI>
__device__ __forceinline__ void gemm_body8(
    const bf16* __restrict__ A, const bf16* __restrict__ Bw,
    const float* __restrict__ bias, const float* __restrict__ qv,
    bf16* __restrict__ C, float* __restrict__ part,
    const int row0, const int col0, const int N, const int K) {
  __shared__ __attribute__((aligned(16))) bf16 L[2][4][8192];  // 128 KB
  const int tid = threadIdx.x;
  const int wid = tid >> 6, lane = tid & 63;
  const int g = lane >> 4, lc = lane & 15;
  const int wr = wid >> 2, wc = wid & 3;  // 2 row-slabs x 4 col-slabs

  const bf16* gA = A + (size_t)(row0 + (tid & 255)) * K + (tid >> 8) * 8;
  const bf16* gB = Bw + (size_t)(col0 + (tid & 255)) * K + (tid >> 8) * 8;
  const int d0 = (tid - lane) * 8;  // wave-uniform LDS dest (elements)

#define STG_A(T, kh) do { \
    const bf16* gp_ = gA + (T) * 64 + (kh) * 32; \
    bf16* lp_ = &L[(T) & 1][(kh)][d0]; \
    GLDS16(gp_, lp_); GLDS16(gp_ + 16, lp_ + 4096); } while (0)
#define STG_B(T, kh) do { \
    const bf16* gp_ = gB + (T) * 64 + (kh) * 32; \
    bf16* lp_ = &L[(T) & 1][2 + (kh)][d0]; \
    GLDS16(gp_, lp_); GLDS16(gp_ + 16, lp_ + 4096); } while (0)
#define RD_A(c, kh) do { \
    _Pragma("unroll") for (int m_ = 0; m_ < 8; ++m_) \
      af[m_] = *(const bf16x8*)&L[c][kh][(g * 256 + wr * 128 + m_ * 16 + lc) * 8]; \
  } while (0)
#define RD_B(c, kh, nh) do { \
    bf[0] = *(const bf16x8*)&L[c][2 + (kh)][(g * 256 + wc * 64 + (nh) * 32 + lc) * 8]; \
    bf[1] = *(const bf16x8*)&L[c][2 + (kh)][(g * 256 + wc * 64 + (nh) * 32 + 16 + lc) * 8]; \
  } while (0)
#define BARS \
    __builtin_amdgcn_s_barrier(); \
    asm volatile("s_waitcnt lgkmcnt(0)" ::: "memory"); \
    __builtin_amdgcn_sched_barrier(0);
#define MM(nh) do { \
    __builtin_amdgcn_s_setprio(1); \
    _Pragma("unroll") for (int m_ = 0; m_ < 8; ++m_) { \
      acc[m_][(nh) * 2 + 0] = MFMA16(af[m_], bf[0], acc[m_][(nh) * 2 + 0]); \
      acc[m_][(nh) * 2 + 1] = MFMA16(af[m_], bf[1], acc[m_][(nh) * 2 + 1]); \
    } \
    __builtin_amdgcn_s_setprio(0); } while (0)
#define ENDP do { \
    __builtin_amdgcn_s_barrier(); \
    asm volatile("" ::: "memory"); \
    __builtin_amdgcn_sched_barrier(0); } while (0)

  const f32x4 z4 = {0.f, 0.f, 0.f, 0.f};
  f32x4 acc[8][4];
#pragma unroll
  for (int m = 0; m < 8; ++m)
#pragma unroll
    for (int n = 0; n < 4; ++n) acc[m][n] = z4;

  bf16x8 af[8], bf[2];
  const int NT = K >> 6;   // K-tiles of 64
  const int NI = NT >> 1;  // iterations (2 tiles each)

  // prologue: tile0 complete + tile1 {A_k0, B_k0, A_k1} = 7 half-tiles
  STG_A(0, 0); STG_B(0, 0); STG_A(0, 1); STG_B(0, 1);
  STG_A(1, 0); STG_B(1, 0); STG_A(1, 1);
  asm volatile("s_waitcnt vmcnt(6)" ::: "memory");  // oldest 8 = tile0 landed
  ENDP;

  for (int i = 0; i < NI; ++i) {
    const int t1 = 2 * i + 1, t2 = 2 * i + 2, t3 = 2 * i + 3;
    const bool p2 = t2 < NT, p3 = t3 < NT;
    // phase 1 (buf0, kh0, nh0)
    RD_A(0, 0); RD_B(0, 0, 0);
    STG_B(t1, 1);
    BARS; MM(0); ENDP;
    // phase 2 (kh0, nh1)
    RD_B(0, 0, 1);
    if (p2) STG_A(t2, 0);
    BARS; MM(1); ENDP;
    // phase 3 (kh1, nh0)
    RD_A(0, 1); RD_B(0, 1, 0);
    if (p2) STG_B(t2, 0);
    BARS; MM(0); ENDP;
    // phase 4 (kh1, nh1) + fence gating buf1 consumption
    RD_B(0, 1, 1);
    if (p2) STG_A(t2, 1);
    BARS; MM(1);
    if (p2) { asm volatile("s_waitcnt vmcnt(6)" ::: "memory"); }
    else    { asm volatile("s_waitcnt vmcnt(0)" ::: "memory"); }
    ENDP;
    // phase 5 (buf1, kh0, nh0)
    RD_A(1, 0); RD_B(1, 0, 0);
    if (p2) STG_B(t2, 1);
    BARS; MM(0); ENDP;
    // phase 6 (kh0, nh1)
    RD_B(1, 0, 1);
    if (p3) STG_A(t3, 0);
    BARS; MM(1); ENDP;
    // phase 7 (kh1, nh0)
    RD_A(1, 1); RD_B(1, 1, 0);
    if (p3) STG_B(t3, 0);
    BARS; MM(0); ENDP;
    // phase 8 (kh1, nh1) + fence gating next-iter buf0 consumption
    RD_B(1, 1, 1);
    if (p3) STG_A(t3, 1);
    BARS; MM(1);
    asm volatile("s_waitcnt vmcnt(6)" ::: "memory");  // trivial on last iter
    ENDP;
  }

#undef STG_A
#undef STG_B
#undef RD_A
#undef RD_B
#undef BARS
#undef MM
#undef ENDP

  if constexpr (EPI == 0) {
#pragma unroll
    for (int n = 0; n < 4; ++n) {
      const int col = col0 + wc * 64 + n * 16 + lc;
      const float bb = bias[col];
#pragma unroll
      for (int m = 0; m < 8; ++m)
#pragma unroll
        for (int r = 0; r < 4; ++r) {
          const int row = row0 + wr * 128 + m * 16 + g * 4 + r;
          C[(size_t)row * N + col] = (bf16)(acc[m][n][r] + bb);
        }
    }
  } else {
    float ps[8][4];
#pragma unroll
    for (int m = 0; m < 8; ++m)
#pragma unroll
      for (int r = 0; r < 4; ++r) ps[m][r] = 0.f;
#pragma unroll
    for (int n = 0; n < 4; ++n) {
      const int col = col0 + wc * 64 + n * 16 + lc;
      const float bb = bias[col];
      const float qq = qv[col];
#pragma unroll
      for (int m = 0; m < 8; ++m)
#pragma unroll
        for (int r = 0; r < 4; ++r)
          ps[m][r] += tanhf(acc[m][n][r] + bb) * qq;
    }
    // plain partial store per 64-col slab: slab = (col0>>8)*4 + wc in [0,16)
    float* pdst = part + (size_t)((col0 >> 8) * 4 + wc) * 8192;
#pragma unroll
    for (int m = 0; m < 8; ++m)
#pragma unroll
      for (int r = 0; r < 4; ++r) {
        float v = ps[m][r];
        v += __shfl_xor(v, 1); v += __shfl_xor(v, 2);
        v += __shfl_xor(v, 4); v += __shfl_xor(v, 8);
        if (lc == 0) {
          const int row = row0 + wr * 128 + m * 16 + g * 4 + r;
          pdst[row] = v;
        }
      }
  }
}

// Swizzle for 128 blocks/GEMM (32 row-tiles x 4 col-tiles, 256^2):
// phys p -> lg = (p&7)*16 + (p>>3); XCD k gets rows [4k,4k+4) x all 4 cols.
__device__ __forceinline__ void swz128(int phys, int& row0, int& col0) {
  const int lg = (phys & 7) * 16 + (phys >> 3);
  row0 = (lg >> 2) * 256;
  col0 = (lg & 3) * 256;
}

struct GemmSet { const bf16* A; const bf16* Bw; const float* bias; bf16* C; };
struct Gemm3Args { GemmSet s[3]; };

__global__ __launch_bounds__(512, 2) void gemm3_kernel(Gemm3Args a) {
  const GemmSet s = a.s[blockIdx.y];
  int row0, col0;
  swz128(blockIdx.x, row0, col0);
  gemm_body8<0>(s.A, s.Bw, s.bias, nullptr, s.C, nullptr, row0, col0, 1024, 1024);
}

__global__ __launch_bounds__(512, 2) void gemm_a_kernel(
    const bf16* __restrict__ A, const bf16* __restrict__ Bw,
    const float* __restrict__ bias, const float* __restrict__ qv,
    float* __restrict__ part) {
  int row0, col0;
  swz128(blockIdx.x, row0, col0);
  gemm_body8<1>(A, Bw, bias, qv, nullptr, part, row0, col0, 1024, 1024);
}

// ---------------------------------------------------------------- attention (validated R4-R11 form)
__global__ __launch_bounds__(256) void attn_kernel(
    const bf16* __restrict__ qp, const bf16* __restrict__ kp,
    const bf16* __restrict__ vp, bf16* __restrict__ xb, float* __restrict__ xf) {
  constexpr int S = 1024, D = 1024;
  __shared__ __attribute__((aligned(16))) bf16 Ks[8192];  // 2x [d/8][64 kv][8]
  __shared__ __attribute__((aligned(16))) bf16 Vs[8192];  // 2x [kv/4][d/16][4][16]
  __shared__ __attribute__((aligned(16))) bf16 Ps[4096];  // per-wave [16 q][64 kv swz]
  const int tid = threadIdx.x, wid = tid >> 6, lane = tid & 63;
  const int g = lane >> 4, lc = lane & 15;
  const int b = blockIdx.x >> 4, h = blockIdx.x & 15;
  const int q0 = blockIdx.y * 64;
  const size_t base = (size_t)b * S * D + (size_t)h * 64;

  bf16x8 qf[2];
  {
    const bf16* qrow = qp + base + (size_t)(q0 + wid * 16 + lc) * D;
    qf[0] = *(const bf16x8*)(qrow + g * 8);
    qf[1] = *(const bf16x8*)(qrow + 32 + g * 8);
#pragma unroll
    for (int j = 0; j < 8; ++j) {
      qf[0][j] = (bf16)((float)qf[0][j] * 0.125f);
      qf[1][j] = (bf16)((float)qf[1][j] * 0.125f);
    }
  }
  float m_s = -1e30f, l_s = 0.f;
  const f32x4 z4 = {0.f, 0.f, 0.f, 0.f};
  f32x4 ax[4];
#pragma unroll
  for (int m = 0; m < 4; ++m) ax[m] = z4;

  const int c0 = tid, c1 = tid + 256;
  const bf16* gK0 = kp + base + (size_t)(c0 & 63) * D + (c0 >> 6) * 8;
  const bf16* gK1 = kp + base + (size_t)(c1 & 63) * D + (c1 >> 6) * 8;
  bf16* lK0 = Ks + (size_t)(c0 - lane) * 8;
  bf16* lK1 = Ks + (size_t)(c1 - lane) * 8;
  const bf16* gV0 = vp + base + (size_t)((c0 >> 5) * 4 + ((c0 >> 1) & 3)) * D +
                    ((c0 >> 3) & 3) * 16 + (c0 & 1) * 8;
  const bf16* gV1 = vp + base + (size_t)((c1 >> 5) * 4 + ((c1 >> 1) & 3)) * D +
                    ((c1 >> 3) & 3) * 16 + (c1 & 1) * 8;
  bf16* lV0 = Vs + (size_t)(c0 - lane) * 8;
  bf16* lV1 = Vs + (size_t)(c1 - lane) * 8;

  bf16* pw = Ps + wid * 1024;
  const int pswz_a = lc & 3, pswz_b = (lc >> 2) & 3;
  const unsigned vaddr0 =
      (unsigned)(uintptr_t)(const __attribute__((address_space(3))) bf16*)(Vs + 512 * g + 4 * lc);

  GLDS16(gK0, lK0);
  GLDS16(gK1, lK1);
  GLDS16(gV0, lV0);
  GLDS16(gV1, lV1);

  for (int t = 0; t < 16; ++t) {
    __syncthreads();
    const int cur = t & 1;
    if (t < 15) {
      const size_t off = (size_t)(t + 1) * 64 * D;
      const int nb = cur ^ 1;
      GLDS16(gK0 + off, lK0 + nb * 4096);
      GLDS16(gK1 + off, lK1 + nb * 4096);
      GLDS16(gV0 + off, lV0 + nb * 4096);
      GLDS16(gV1 + off, lV1 + nb * 4096);
    }
    const bf16* Kb = Ks + cur * 4096;
    const unsigned va = vaddr0 + cur * 8192u;

    f32x4 sc[4];
    __builtin_amdgcn_s_setprio(1);
#pragma unroll
    for (int m = 0; m < 4; ++m) {
      f32x4 z = z4;
      bf16x8 kf0 = *(const bf16x8*)(Kb + (size_t)g * 512 + (m * 16 + lc) * 8);
      bf16x8 kf1 = *(const bf16x8*)(Kb + (size_t)(4 + g) * 512 + (m * 16 + lc) * 8);
      z = MFMA16(kf0, qf[0], z);
      z = MFMA16(kf1, qf[1], z);
      sc[m] = z;
    }
    __builtin_amdgcn_s_setprio(0);

    float mx = -1e30f;
#pragma unroll
    for (int m = 0; m < 4; ++m)
      mx = fmaxf(mx, fmaxf(fmaxf(sc[m][0], sc[m][1]), fmaxf(sc[m][2], sc[m][3])));
    mx = fmaxf(mx, __shfl_xor(mx, 16));
    mx = fmaxf(mx, __shfl_xor(mx, 32));
    if (!__all(mx - m_s <= 8.f)) {
      const float mn = fmaxf(m_s, mx);
      const float cr = __expf(m_s - mn);
      l_s *= cr;
#pragma unroll
      for (int m = 0; m < 4; ++m) ax[m] *= cr;
      m_s = mn;
    }
    float sm = 0.f;
#pragma unroll
    for (int m = 0; m < 4; ++m)
#pragma unroll
      for (int r = 0; r < 4; ++r) {
        float p = __expf(sc[m][r] - m_s);
        sc[m][r] = p;
        sm += p;
      }
    sm += __shfl_xor(sm, 16);
    sm += __shfl_xor(sm, 32);
    l_s += sm;

#pragma unroll
    for (int m = 0; m < 4; ++m) {
      bf16x4 pk;
      pk[0] = (bf16)sc[m][0]; pk[1] = (bf16)sc[m][1];
      pk[2] = (bf16)sc[m][2]; pk[3] = (bf16)sc[m][3];
      *(bf16x4*)(pw + lc * 64 + 16 * (m ^ pswz_a) + 4 * (g ^ pswz_b)) = pk;
    }

    bf16x4 pr[2][2];
#pragma unroll
    for (int kk = 0; kk < 2; ++kk)
#pragma unroll
      for (int jh = 0; jh < 2; ++jh) {
        const int msrc = 2 * kk + (g >> 1);
        const int gsrc = (2 * g + jh) & 3;
        pr[kk][jh] = *(const bf16x4*)(pw + lc * 64 + 16 * (msrc ^ pswz_a) + 4 * (gsrc ^ pswz_b));
      }
    bf16x8 pf0 = __builtin_shufflevector(pr[0][0], pr[0][1], 0, 1, 2, 3, 4, 5, 6, 7);
    bf16x8 pf1 = __builtin_shufflevector(pr[1][0], pr[1][1], 0, 1, 2, 3, 4, 5, 6, 7);

    bf16x4 vt[4][2][2];
    TR16(vt[0][0][0], va, 0);    TR16(vt[1][0][0], va, 128);
    TR16(vt[2][0][0], va, 256);  TR16(vt[3][0][0], va, 384);
    TR16(vt[0][0][1], va, 512);  TR16(vt[1][0][1], va, 640);
    TR16(vt[2][0][1], va, 768);  TR16(vt[3][0][1], va, 896);
    TR16(vt[0][1][0], va, 4096); TR16(vt[1][1][0], va, 4224);
    TR16(vt[2][1][0], va, 4352); TR16(vt[3][1][0], va, 4480);
    TR16(vt[0][1][1], va, 4608); TR16(vt[1][1][1], va, 4736);
    TR16(vt[2][1][1], va, 4864); TR16(vt[3][1][1], va, 4992);
    asm volatile("s_waitcnt lgkmcnt(0)" ::: "memory");
    __builtin_amdgcn_sched_barrier(0);

    __builtin_amdgcn_s_setprio(1);
#pragma unroll
    for (int md = 0; md < 4; ++md) {
      bf16x8 a0 = __builtin_shufflevector(vt[md][0][0], vt[md][0][1], 0, 1, 2, 3, 4, 5, 6, 7);
      bf16x8 a1 = __builtin_shufflevector(vt[md][1][0], vt[md][1][1], 0, 1, 2, 3, 4, 5, 6, 7);
      ax[md] = MFMA16(a0, pf0, ax[md]);
      ax[md] = MFMA16(a1, pf1, ax[md]);
    }
    __builtin_amdgcn_s_setprio(0);
  }

  const float inv = 1.0f / l_s;
  const int qrow = q0 + wid * 16 + lc;
  float* xfr = xf + base + (size_t)qrow * D;
  bf16* xbr = xb + base + (size_t)qrow * D;
#pragma unroll
  for (int m = 0; m < 4; ++m) {
    f32x4 vv = ax[m] * inv;
    *(f32x4*)(xfr + 16 * m + 4 * g) = vv;
    bf16x4 bb;
    bb[0] = (bf16)vv[0]; bb[1] = (bf16)vv[1];
    bb[2] = (bf16)vv[2]; bb[3] = (bf16)vv[3];
    *(bf16x4*)(xbr + 16 * m + 4 * g) = bb;
  }
}

// ---------------------------------------------------------------- alpha softmax (from part slabs)
// 8 blocks (one per batch), 256 threads. part: [16][8192] partial tanh-dots.
__global__ __launch_bounds__(256) void softmax_part(const float* __restrict__ part,
                                                    float* __restrict__ alpha) {
  __shared__ float red[8];
  const int b = blockIdx.x, t = threadIdx.x;
  f32x4 a4 = {0.f, 0.f, 0.f, 0.f};
#pragma unroll
  for (int p = 0; p < 16; ++p) {
    const float* pp = part + (size_t)p * 8192 + b * 1024 + t * 4;
    a4[0] += pp[0]; a4[1] += pp[1]; a4[2] += pp[2]; a4[3] += pp[3];
  }
  float m = fmaxf(fmaxf(a4[0], a4[1]), fmaxf(a4[2], a4[3]));
#pragma unroll
  for (int o = 1; o < 64; o <<= 1) m = fmaxf(m, __shfl_xor(m, o));
  if ((t & 63) == 0) red[t >> 6] = m;
  __syncthreads();
  m = fmaxf(fmaxf(red[0], red[1]), fmaxf(red[2], red[3]));
  f32x4 e;
  float s = 0.f;
#pragma unroll
  for (int j = 0; j < 4; ++j) { e[j] = __expf(a4[j] - m); s += e[j]; }
#pragma unroll
  for (int o = 1; o < 64; o <<= 1) s += __shfl_xor(s, o);
  if ((t & 63) == 0) red[4 + (t >> 6)] = s;
  __syncthreads();
  const float inv = 1.0f / (red[4] + red[5] + red[6] + red[7]);
  *(f32x4*)(alpha + b * 1024 + t * 4) = e * inv;
}

// ---------------------------------------------------------------- pooling (wide grid, validated R1-R9)
__global__ __launch_bounds__(256) void pool_kernel(const float* __restrict__ xf,
                                                   const float* __restrict__ alpha,
                                                   float* __restrict__ out) {
  const int b = blockIdx.y, sc = blockIdx.x, t = threadIdx.x;
  f32x4 acc = {0.f, 0.f, 0.f, 0.f};
  const float* xrow = xf + (size_t)b * 1024 * 1024;
  for (int s = sc * 64; s < sc * 64 + 64; ++s) {
    const float al = alpha[b * 1024 + s];
    f32x4 xv = *(const f32x4*)(xrow + (size_t)s * 1024 + t * 4);
    acc += xv * al;
  }
  atomicAdd(&out[b * 1024 + t * 4 + 0], acc[0]);
  atomicAdd(&out[b * 1024 + t * 4 + 1], acc[1]);
  atomicAdd(&out[b * 1024 + t * 4 + 2], acc[2]);
  atomicAdd(&out[b * 1024 + t * 4 + 3], acc[3]);
}

// ---------------------------------------------------------------- launch
extern "C" void kernel_launch(void* const* d_in, const int* in_sizes, int n_in,
                              void* d_out, int out_size, void* d_ws, size_t ws_size,
                              hipStream_t stream) {
  const float* Q   = (const float*)d_in[0];
  const float* K   = (const float*)d_in[1];
  const float* V   = (const float*)d_in[2];
  const float* Wq  = (const float*)d_in[3];
  const float* bq  = (const float*)d_in[4];
  const float* Wk  = (const float*)d_in[5];
  const float* bk  = (const float*)d_in[6];
  const float* Wv  = (const float*)d_in[7];
  const float* bv  = (const float*)d_in[8];
  const float* Wa  = (const float*)d_in[9];
  const float* ba  = (const float*)d_in[10];
  const float* qvec = (const float*)d_in[11];
  float* out = (float*)d_out;
  char* ws = (char*)d_ws;
  const size_t MB = 1ull << 20;

  bf16* Wqb = (bf16*)(ws + 0 * MB);
  bf16* Wkb = (bf16*)(ws + 2 * MB);
  bf16* Wvb = (bf16*)(ws + 4 * MB);
  bf16* Wab = (bf16*)(ws + 6 * MB);
  bf16* qb  = (bf16*)(ws + 8 * MB);
  bf16* kb  = (bf16*)(ws + 24 * MB);
  bf16* vb  = (bf16*)(ws + 40 * MB);
  bf16* qp  = (bf16*)(ws + 56 * MB);
  bf16* kp  = (bf16*)(ws + 72 * MB);
  bf16* vp  = (bf16*)(ws + 88 * MB);
  float* part  = (float*)(ws + 104 * MB);             // [16][8192] f32 = 512 KB
  float* alpha = (float*)(ws + 104 * MB + 524288);    // [8][1024]
  bf16* xb  = qb;                       // qb dead after Q projection
  float* xf = (float*)(ws + 24 * MB);   // kb+vb dead after K/V projections

  // out zeroing up front (pool accumulates via atomicAdd)
  hipMemsetAsync(out, 0, 8192 * sizeof(float), stream);

  // all f32 -> bf16 conversions in one dispatch
  CvtAll cv = {{Q, K, V, Wq, Wk, Wv, Wa}, {qb, kb, vb, Wqb, Wkb, Wvb, Wab}};
  f2b_all<<<dim3(4096, 4), 256, 0, stream>>>(cv);

  // projections: one dispatch, y = {q,k,v}; 128 swizzled 256^2 blocks per GEMM
  Gemm3Args g3 = {{{qb, Wqb, bq, qp}, {kb, Wkb, bk, kp}, {vb, Wvb, bv, vp}}};
  gemm3_kernel<<<dim3(128, 3), 512, 0, stream>>>(g3);

  // flash attention
  attn_kernel<<<dim3(128, 16), 256, 0, stream>>>(qp, kp, vp, xb, xf);

  // pooling head partials: part[slab][row] = sum_{n in slab} tanh(xWa^T+ba)*qv
  gemm_a_kernel<<<128, 512, 0, stream>>>(xb, Wab, ba, qvec, part);

  // alpha softmax (8 blocks, reads 512KB part) + wide-grid pooling (128 blocks)
  softmax_part<<<8, 256, 0, stream>>>(part, alpha);
  pool_kernel<<<dim3(16, 8), 256, 0, stream>>>(xf, alpha, out);
}

// Round 13
// 245.423 us; speedup vs baseline: 1.2093x; 1.0725x over previous
//
#include <hip/hip_runtime.h>

typedef __bf16 bf16;
typedef __attribute__((ext_vector_type(8))) __bf16 bf16x8;
typedef __attribute__((ext_vector_type(4))) __bf16 bf16x4;
typedef __attribute__((ext_vector_type(4))) float f32x4;

#define GLDS16(g, l) __builtin_amdgcn_global_load_lds( \
    (const __attribute__((address_space(1))) void*)(g), \
    (__attribute__((address_space(3))) void*)(l), 16, 0, 0)

#define MFMA16(a, b, c) __builtin_amdgcn_mfma_f32_16x16x32_bf16(a, b, c, 0, 0, 0)

// ds_read_b64_tr_b16: per-lane gather of 4 bf16 at 32B stride (HW transpose read)
#define TR16(dst, addr, off) \
  asm volatile("ds_read_b64_tr_b16 %0, %1 offset:" #off : "=v"(dst) : "v"(addr))

// ---------------------------------------------------------------- convert (all 7 tensors, 1 dispatch)
struct CvtAll { const float* in[7]; bf16* out[7]; };

__global__ __launch_bounds__(256) void f2b_all(CvtAll a) {
  const int i = blockIdx.x * 256 + threadIdx.x;
  const float* in;
  bf16* out;
  int off;
  if (blockIdx.y < 3) {            // Q, K, V: 1048576 8-chunks each
    in = a.in[blockIdx.y];
    out = a.out[blockIdx.y];
    off = i;
  } else {                          // 4 weights: 131072 8-chunks each
    if (i >= 524288) return;
    const int widx = 3 + (i >> 17);
    in = a.in[widx];
    out = a.out[widx];
    off = i & 131071;
  }
  const f32x4* p = (const f32x4*)in + (size_t)off * 2;
  f32x4 x = p[0], y = p[1];
  bf16x8 o;
  o[0] = (bf16)x[0]; o[1] = (bf16)x[1]; o[2] = (bf16)x[2]; o[3] = (bf16)x[3];
  o[4] = (bf16)y[0]; o[5] = (bf16)y[1]; o[6] = (bf16)y[2]; o[7] = (bf16)y[3];
  ((bf16x8*)out)[off] = o;
}

// ---------------------------------------------------------------- GEMM 8-phase (hardened barriers)
// C[m,n] = sum_k A[m,k] * Bw[n,k]  (+bias[n])
// BM = MF*32 (MF=8 -> 256x256, 128 KB LDS; MF=4 -> 128x256, 96 KB LDS),
// BN=256, BK=64, 8 waves (2Mx4N). 8-phase counted-vmcnt schedule; ENDP =
// s_barrier + compiler memory fence + sched fence (R10's post-timing race
// was next-phase ds_reads hoisted above a bare s_barrier).
// Gate count: in-flight loads after the gated half-tile = STGA+2+STGA where
// STGA = MF/4 GLDS per thread -> vmcnt(6) for MF=8, vmcnt(4) for MF=4.
// EPI==0: store bf16 C (+bias).
// EPI==1: part[(col0>>8)*4 + wc][row] = sum_{n in 64-col slab} tanh(C+bias)*qv
template <int EPI, int MF>
__device__ __forceinline__ void gemm_body8(
    const bf16* __restrict__ A, const bf16* __restrict__ Bw,
    const float* __restrict__ bias, const float* __restrict__ qv,
    bf16* __restrict__ C, float* __restrict__ part,
    const int row0, const int col0, const int N, const int K) {
  constexpr int BM = MF * 32;
  constexpr int ASZ = MF * 1024;         // A region elems (BM x 32k)
  constexpr int BUF = 2 * ASZ + 16384;   // per-buffer elems (2 A + 2 B regions)
  constexpr int RSH = (MF == 8) ? 8 : 7; // chunk shift for A staging
  __shared__ __attribute__((aligned(16))) bf16 L[2 * BUF];
  const int tid = threadIdx.x;
  const int wid = tid >> 6, lane = tid & 63;
  const int g = lane >> 4, lc = lane & 15;
  const int wr = wid >> 2, wc = wid & 3;  // 2 row-slabs x 4 col-slabs

  const bf16* gA = A + (size_t)(row0 + (tid & (BM - 1))) * K + (tid >> RSH) * 8;
  const bf16* gB = Bw + (size_t)(col0 + (tid & 255)) * K + (tid >> 8) * 8;
  const int d0 = (tid - lane) * 8;  // wave-uniform LDS dest (elements)

#define STG_A(T, kh) do { \
    const bf16* gp_ = gA + (T) * 64 + (kh) * 32; \
    bf16* lp_ = L + ((T) & 1) * BUF + (kh) * ASZ + d0; \
    GLDS16(gp_, lp_); \
    if constexpr (MF == 8) GLDS16(gp_ + 16, lp_ + 4096); } while (0)
#define STG_B(T, kh) do { \
    const bf16* gp_ = gB + (T) * 64 + (kh) * 32; \
    bf16* lp_ = L + ((T) & 1) * BUF + 2 * ASZ + (kh) * 8192 + d0; \
    GLDS16(gp_, lp_); GLDS16(gp_ + 16, lp_ + 4096); } while (0)
#define RD_A(c, kh) do { \
    _Pragma("unroll") for (int m_ = 0; m_ < MF; ++m_) \
      af[m_] = *(const bf16x8*)&L[(c) * BUF + (kh) * ASZ + g * (BM * 8) + \
                                  (wr * (MF * 16) + m_ * 16 + lc) * 8]; \
  } while (0)
#define RD_B(c, kh, nh) do { \
    bf[0] = *(const bf16x8*)&L[(c) * BUF + 2 * ASZ + (kh) * 8192 + g * 2048 + \
                               (wc * 64 + (nh) * 32 + lc) * 8]; \
    bf[1] = *(const bf16x8*)&L[(c) * BUF + 2 * ASZ + (kh) * 8192 + g * 2048 + \
                               (wc * 64 + (nh) * 32 + 16 + lc) * 8]; \
  } while (0)
#define BARS \
    __builtin_amdgcn_s_barrier(); \
    asm volatile("s_waitcnt lgkmcnt(0)" ::: "memory"); \
    __builtin_amdgcn_sched_barrier(0);
#define MM(nh) do { \
    __builtin_amdgcn_s_setprio(1); \
    _Pragma("unroll") for (int m_ = 0; m_ < MF; ++m_) { \
      acc[m_][(nh) * 2 + 0] = MFMA16(af[m_], bf[0], acc[m_][(nh) * 2 + 0]); \
      acc[m_][(nh) * 2 + 1] = MFMA16(af[m_], bf[1], acc[m_][(nh) * 2 + 1]); \
    } \
    __builtin_amdgcn_s_setprio(0); } while (0)
#define ENDP do { \
    __builtin_amdgcn_s_barrier(); \
    asm volatile("" ::: "memory"); \
    __builtin_amdgcn_sched_barrier(0); } while (0)
#define VGATE() do { \
    if constexpr (MF == 8) { asm volatile("s_waitcnt vmcnt(6)" ::: "memory"); } \
    else                   { asm volatile("s_waitcnt vmcnt(4)" ::: "memory"); } } while (0)

  const f32x4 z4 = {0.f, 0.f, 0.f, 0.f};
  f32x4 acc[MF][4];
#pragma unroll
  for (int m = 0; m < MF; ++m)
#pragma unroll
    for (int n = 0; n < 4; ++n) acc[m][n] = z4;

  bf16x8 af[MF], bf[2];
  const int NT = K >> 6;   // K-tiles of 64
  const int NI = NT >> 1;  // iterations (2 tiles each)

  // prologue: tile0 complete + tile1 {A_k0, B_k0, A_k1}
  STG_A(0, 0); STG_B(0, 0); STG_A(0, 1); STG_B(0, 1);
  STG_A(1, 0); STG_B(1, 0); STG_A(1, 1);
  VGATE();  // tile0's loads landed; tile1's partial stays in flight
  ENDP;

  for (int i = 0; i < NI; ++i) {
    const int t1 = 2 * i + 1, t2 = 2 * i + 2, t3 = 2 * i + 3;
    const bool p2 = t2 < NT, p3 = t3 < NT;
    // phase 1 (buf0, kh0, nh0)
    RD_A(0, 0); RD_B(0, 0, 0);
    STG_B(t1, 1);
    BARS; MM(0); ENDP;
    // phase 2 (kh0, nh1)
    RD_B(0, 0, 1);
    if (p2) STG_A(t2, 0);
    BARS; MM(1); ENDP;
    // phase 3 (kh1, nh0)
    RD_A(0, 1); RD_B(0, 1, 0);
    if (p2) STG_B(t2, 0);
    BARS; MM(0); ENDP;
    // phase 4 (kh1, nh1) + fence gating buf1 consumption
    RD_B(0, 1, 1);
    if (p2) STG_A(t2, 1);
    BARS; MM(1);
    if (p2) { VGATE(); }
    else    { asm volatile("s_waitcnt vmcnt(0)" ::: "memory"); }
    ENDP;
    // phase 5 (buf1, kh0, nh0)
    RD_A(1, 0); RD_B(1, 0, 0);
    if (p2) STG_B(t2, 1);
    BARS; MM(0); ENDP;
    // phase 6 (kh0, nh1)
    RD_B(1, 0, 1);
    if (p3) STG_A(t3, 0);
    BARS; MM(1); ENDP;
    // phase 7 (kh1, nh0)
    RD_A(1, 1); RD_B(1, 1, 0);
    if (p3) STG_B(t3, 0);
    BARS; MM(0); ENDP;
    // phase 8 (kh1, nh1) + fence gating next-iter buf0 consumption
    RD_B(1, 1, 1);
    if (p3) STG_A(t3, 1);
    BARS; MM(1);
    VGATE();  // trivial on last iter
    ENDP;
  }

#undef STG_A
#undef STG_B
#undef RD_A
#undef RD_B
#undef BARS
#undef MM
#undef ENDP
#undef VGATE

  if constexpr (EPI == 0) {
#pragma unroll
    for (int n = 0; n < 4; ++n) {
      const int col = col0 + wc * 64 + n * 16 + lc;
      const float bb = bias[col];
#pragma unroll
      for (int m = 0; m < MF; ++m)
#pragma unroll
        for (int r = 0; r < 4; ++r) {
          const int row = row0 + wr * (MF * 16) + m * 16 + g * 4 + r;
          C[(size_t)row * N + col] = (bf16)(acc[m][n][r] + bb);
        }
    }
  } else {
    float ps[MF][4];
#pragma unroll
    for (int m = 0; m < MF; ++m)
#pragma unroll
      for (int r = 0; r < 4; ++r) ps[m][r] = 0.f;
#pragma unroll
    for (int n = 0; n < 4; ++n) {
      const int col = col0 + wc * 64 + n * 16 + lc;
      const float bb = bias[col];
      const float qq = qv[col];
#pragma unroll
      for (int m = 0; m < MF; ++m)
#pragma unroll
        for (int r = 0; r < 4; ++r)
          ps[m][r] += tanhf(acc[m][n][r] + bb) * qq;
    }
    // plain partial store per 64-col slab: slab = (col0>>8)*4 + wc in [0,16)
    float* pdst = part + (size_t)((col0 >> 8) * 4 + wc) * 8192;
#pragma unroll
    for (int m = 0; m < MF; ++m)
#pragma unroll
      for (int r = 0; r < 4; ++r) {
        float v = ps[m][r];
        v += __shfl_xor(v, 1); v += __shfl_xor(v, 2);
        v += __shfl_xor(v, 4); v += __shfl_xor(v, 8);
        if (lc == 0) {
          const int row = row0 + wr * (MF * 16) + m * 16 + g * 4 + r;
          pdst[row] = v;
        }
      }
  }
}

// Swizzle for 128 blocks/GEMM (32 row-tiles x 4 col-tiles, 256^2):
// phys p -> lg = (p&7)*16 + (p>>3); XCD k gets rows [4k,4k+4) x all 4 cols.
__device__ __forceinline__ void swz128(int phys, int& row0, int& col0) {
  const int lg = (phys & 7) * 16 + (phys >> 3);
  row0 = (lg >> 2) * 256;
  col0 = (lg & 3) * 256;
}

// Swizzle for 256 blocks (64 row-tiles of 128 x 4 col-tiles of 256). Bijective
// (256 % 8 == 0); XCD k gets a contiguous row band x all 4 cols.
__device__ __forceinline__ void swz256(int phys, int& row0, int& col0) {
  const int lg = (phys & 7) * 32 + (phys >> 3);
  row0 = (lg >> 2) * 128;
  col0 = (lg & 3) * 256;
}

struct GemmSet { const bf16* A; const bf16* Bw; const float* bias; bf16* C; };
struct Gemm3Args { GemmSet s[3]; };

__global__ __launch_bounds__(512, 2) void gemm3_kernel(Gemm3Args a) {
  const GemmSet s = a.s[blockIdx.y];
  int row0, col0;
  swz128(blockIdx.x, row0, col0);
  gemm_body8<0, 8>(s.A, s.Bw, s.bias, nullptr, s.C, nullptr, row0, col0, 1024, 1024);
}

// 128x256 tiles -> 256 blocks = one full-chip round (vs 128 blocks = half idle)
__global__ __launch_bounds__(512, 2) void gemm_a_kernel(
    const bf16* __restrict__ A, const bf16* __restrict__ Bw,
    const float* __restrict__ bias, const float* __restrict__ qv,
    float* __restrict__ part) {
  int row0, col0;
  swz256(blockIdx.x, row0, col0);
  gemm_body8<1, 4>(A, Bw, bias, qv, nullptr, part, row0, col0, 1024, 1024);
}

// ---------------------------------------------------------------- attention (validated R4-R12 form)
__global__ __launch_bounds__(256) void attn_kernel(
    const bf16* __restrict__ qp, const bf16* __restrict__ kp,
    const bf16* __restrict__ vp, bf16* __restrict__ xb, float* __restrict__ xf) {
  constexpr int S = 1024, D = 1024;
  __shared__ __attribute__((aligned(16))) bf16 Ks[8192];  // 2x [d/8][64 kv][8]
  __shared__ __attribute__((aligned(16))) bf16 Vs[8192];  // 2x [kv/4][d/16][4][16]
  __shared__ __attribute__((aligned(16))) bf16 Ps[4096];  // per-wave [16 q][64 kv swz]
  const int tid = threadIdx.x, wid = tid >> 6, lane = tid & 63;
  const int g = lane >> 4, lc = lane & 15;
  const int b = blockIdx.x >> 4, h = blockIdx.x & 15;
  const int q0 = blockIdx.y * 64;
  const size_t base = (size_t)b * S * D + (size_t)h * 64;

  bf16x8 qf[2];
  {
    const bf16* qrow = qp + base + (size_t)(q0 + wid * 16 + lc) * D;
    qf[0] = *(const bf16x8*)(qrow + g * 8);
    qf[1] = *(const bf16x8*)(qrow + 32 + g * 8);
#pragma unroll
    for (int j = 0; j < 8; ++j) {
      qf[0][j] = (bf16)((float)qf[0][j] * 0.125f);
      qf[1][j] = (bf16)((float)qf[1][j] * 0.125f);
    }
  }
  float m_s = -1e30f, l_s = 0.f;
  const f32x4 z4 = {0.f, 0.f, 0.f, 0.f};
  f32x4 ax[4];
#pragma unroll
  for (int m = 0; m < 4; ++m) ax[m] = z4;

  const int c0 = tid, c1 = tid + 256;
  const bf16* gK0 = kp + base + (size_t)(c0 & 63) * D + (c0 >> 6) * 8;
  const bf16* gK1 = kp + base + (size_t)(c1 & 63) * D + (c1 >> 6) * 8;
  bf16* lK0 = Ks + (size_t)(c0 - lane) * 8;
  bf16* lK1 = Ks + (size_t)(c1 - lane) * 8;
  const bf16* gV0 = vp + base + (size_t)((c0 >> 5) * 4 + ((c0 >> 1) & 3)) * D +
                    ((c0 >> 3) & 3) * 16 + (c0 & 1) * 8;
  const bf16* gV1 = vp + base + (size_t)((c1 >> 5) * 4 + ((c1 >> 1) & 3)) * D +
                    ((c1 >> 3) & 3) * 16 + (c1 & 1) * 8;
  bf16* lV0 = Vs + (size_t)(c0 - lane) * 8;
  bf16* lV1 = Vs + (size_t)(c1 - lane) * 8;

  bf16* pw = Ps + wid * 1024;
  const int pswz_a = lc & 3, pswz_b = (lc >> 2) & 3;
  const unsigned vaddr0 =
      (unsigned)(uintptr_t)(const __attribute__((address_space(3))) bf16*)(Vs + 512 * g + 4 * lc);

  GLDS16(gK0, lK0);
  GLDS16(gK1, lK1);
  GLDS16(gV0, lV0);
  GLDS16(gV1, lV1);

  for (int t = 0; t < 16; ++t) {
    __syncthreads();
    const int cur = t & 1;
    if (t < 15) {
      const size_t off = (size_t)(t + 1) * 64 * D;
      const int nb = cur ^ 1;
      GLDS16(gK0 + off, lK0 + nb * 4096);
      GLDS16(gK1 + off, lK1 + nb * 4096);
      GLDS16(gV0 + off, lV0 + nb * 4096);
      GLDS16(gV1 + off, lV1 + nb * 4096);
    }
    const bf16* Kb = Ks + cur * 4096;
    const unsigned va = vaddr0 + cur * 8192u;

    f32x4 sc[4];
    __builtin_amdgcn_s_setprio(1);
#pragma unroll
    for (int m = 0; m < 4; ++m) {
      f32x4 z = z4;
      bf16x8 kf0 = *(const bf16x8*)(Kb + (size_t)g * 512 + (m * 16 + lc) * 8);
      bf16x8 kf1 = *(const bf16x8*)(Kb + (size_t)(4 + g) * 512 + (m * 16 + lc) * 8);
      z = MFMA16(kf0, qf[0], z);
      z = MFMA16(kf1, qf[1], z);
      sc[m] = z;
    }
    __builtin_amdgcn_s_setprio(0);

    float mx = -1e30f;
#pragma unroll
    for (int m = 0; m < 4; ++m)
      mx = fmaxf(mx, fmaxf(fmaxf(sc[m][0], sc[m][1]), fmaxf(sc[m][2], sc[m][3])));
    mx = fmaxf(mx, __shfl_xor(mx, 16));
    mx = fmaxf(mx, __shfl_xor(mx, 32));
    if (!__all(mx - m_s <= 8.f)) {
      const float mn = fmaxf(m_s, mx);
      const float cr = __expf(m_s - mn);
      l_s *= cr;
#pragma unroll
      for (int m = 0; m < 4; ++m) ax[m] *= cr;
      m_s = mn;
    }
    float sm = 0.f;
#pragma unroll
    for (int m = 0; m < 4; ++m)
#pragma unroll
      for (int r = 0; r < 4; ++r) {
        float p = __expf(sc[m][r] - m_s);
        sc[m][r] = p;
        sm += p;
      }
    sm += __shfl_xor(sm, 16);
    sm += __shfl_xor(sm, 32);
    l_s += sm;

#pragma unroll
    for (int m = 0; m < 4; ++m) {
      bf16x4 pk;
      pk[0] = (bf16)sc[m][0]; pk[1] = (bf16)sc[m][1];
      pk[2] = (bf16)sc[m][2]; pk[3] = (bf16)sc[m][3];
      *(bf16x4*)(pw + lc * 64 + 16 * (m ^ pswz_a) + 4 * (g ^ pswz_b)) = pk;
    }

    bf16x4 pr[2][2];
#pragma unroll
    for (int kk = 0; kk < 2; ++kk)
#pragma unroll
      for (int jh = 0; jh < 2; ++jh) {
        const int msrc = 2 * kk + (g >> 1);
        const int gsrc = (2 * g + jh) & 3;
        pr[kk][jh] = *(const bf16x4*)(pw + lc * 64 + 16 * (msrc ^ pswz_a) + 4 * (gsrc ^ pswz_b));
      }
    bf16x8 pf0 = __builtin_shufflevector(pr[0][0], pr[0][1], 0, 1, 2, 3, 4, 5, 6, 7);
    bf16x8 pf1 = __builtin_shufflevector(pr[1][0], pr[1][1], 0, 1, 2, 3, 4, 5, 6, 7);

    bf16x4 vt[4][2][2];
    TR16(vt[0][0][0], va, 0);    TR16(vt[1][0][0], va, 128);
    TR16(vt[2][0][0], va, 256);  TR16(vt[3][0][0], va, 384);
    TR16(vt[0][0][1], va, 512);  TR16(vt[1][0][1], va, 640);
    TR16(vt[2][0][1], va, 768);  TR16(vt[3][0][1], va, 896);
    TR16(vt[0][1][0], va, 4096); TR16(vt[1][1][0], va, 4224);
    TR16(vt[2][1][0], va, 4352); TR16(vt[3][1][0], va, 4480);
    TR16(vt[0][1][1], va, 4608); TR16(vt[1][1][1], va, 4736);
    TR16(vt[2][1][1], va, 4864); TR16(vt[3][1][1], va, 4992);
    asm volatile("s_waitcnt lgkmcnt(0)" ::: "memory");
    __builtin_amdgcn_sched_barrier(0);

    __builtin_amdgcn_s_setprio(1);
#pragma unroll
    for (int md = 0; md < 4; ++md) {
      bf16x8 a0 = __builtin_shufflevector(vt[md][0][0], vt[md][0][1], 0, 1, 2, 3, 4, 5, 6, 7);
      bf16x8 a1 = __builtin_shufflevector(vt[md][1][0], vt[md][1][1], 0, 1, 2, 3, 4, 5, 6, 7);
      ax[md] = MFMA16(a0, pf0, ax[md]);
      ax[md] = MFMA16(a1, pf1, ax[md]);
    }
    __builtin_amdgcn_s_setprio(0);
  }

  const float inv = 1.0f / l_s;
  const int qrow = q0 + wid * 16 + lc;
  float* xfr = xf + base + (size_t)qrow * D;
  bf16* xbr = xb + base + (size_t)qrow * D;
#pragma unroll
  for (int m = 0; m < 4; ++m) {
    f32x4 vv = ax[m] * inv;
    *(f32x4*)(xfr + 16 * m + 4 * g) = vv;
    bf16x4 bb;
    bb[0] = (bf16)vv[0]; bb[1] = (bf16)vv[1];
    bb[2] = (bf16)vv[2]; bb[3] = (bf16)vv[3];
    *(bf16x4*)(xbr + 16 * m + 4 * g) = bb;
  }
}

// ---------------------------------------------------------------- alpha softmax (from part slabs)
__global__ __launch_bounds__(256) void softmax_part(const float* __restrict__ part,
                                                    float* __restrict__ alpha) {
  __shared__ float red[8];
  const int b = blockIdx.x, t = threadIdx.x;
  f32x4 a4 = {0.f, 0.f, 0.f, 0.f};
#pragma unroll
  for (int p = 0; p < 16; ++p) {
    const float* pp = part + (size_t)p * 8192 + b * 1024 + t * 4;
    a4[0] += pp[0]; a4[1] += pp[1]; a4[2] += pp[2]; a4[3] += pp[3];
  }
  float m = fmaxf(fmaxf(a4[0], a4[1]), fmaxf(a4[2], a4[3]));
#pragma unroll
  for (int o = 1; o < 64; o <<= 1) m = fmaxf(m, __shfl_xor(m, o));
  if ((t & 63) == 0) red[t >> 6] = m;
  __syncthreads();
  m = fmaxf(fmaxf(red[0], red[1]), fmaxf(red[2], red[3]));
  f32x4 e;
  float s = 0.f;
#pragma unroll
  for (int j = 0; j < 4; ++j) { e[j] = __expf(a4[j] - m); s += e[j]; }
#pragma unroll
  for (int o = 1; o < 64; o <<= 1) s += __shfl_xor(s, o);
  if ((t & 63) == 0) red[4 + (t >> 6)] = s;
  __syncthreads();
  const float inv = 1.0f / (red[4] + red[5] + red[6] + red[7]);
  *(f32x4*)(alpha + b * 1024 + t * 4) = e * inv;
}

// ---------------------------------------------------------------- pooling (wide grid, validated)
__global__ __launch_bounds__(256) void pool_kernel(const float* __restrict__ xf,
                                                   const float* __restrict__ alpha,
                                                   float* __restrict__ out) {
  const int b = blockIdx.y, sc = blockIdx.x, t = threadIdx.x;
  f32x4 acc = {0.f, 0.f, 0.f, 0.f};
  const float* xrow = xf + (size_t)b * 1024 * 1024;
  for (int s = sc * 64; s < sc * 64 + 64; ++s) {
    const float al = alpha[b * 1024 + s];
    f32x4 xv = *(const f32x4*)(xrow + (size_t)s * 1024 + t * 4);
    acc += xv * al;
  }
  atomicAdd(&out[b * 1024 + t * 4 + 0], acc[0]);
  atomicAdd(&out[b * 1024 + t * 4 + 1], acc[1]);
  atomicAdd(&out[b * 1024 + t * 4 + 2], acc[2]);
  atomicAdd(&out[b * 1024 + t * 4 + 3], acc[3]);
}

// ---------------------------------------------------------------- launch
extern "C" void kernel_launch(void* const* d_in, const int* in_sizes, int n_in,
                              void* d_out, int out_size, void* d_ws, size_t ws_size,
                              hipStream_t stream) {
  const float* Q   = (const float*)d_in[0];
  const float* K   = (const float*)d_in[1];
  const float* V   = (const float*)d_in[2];
  const float* Wq  = (const float*)d_in[3];
  const float* bq  = (const float*)d_in[4];
  const float* Wk  = (const float*)d_in[5];
  const float* bk  = (const float*)d_in[6];
  const float* Wv  = (const float*)d_in[7];
  const float* bv  = (const float*)d_in[8];
  const float* Wa  = (const float*)d_in[9];
  const float* ba  = (const float*)d_in[10];
  const float* qvec = (const float*)d_in[11];
  float* out = (float*)d_out;
  char* ws = (char*)d_ws;
  const size_t MB = 1ull << 20;

  bf16* Wqb = (bf16*)(ws + 0 * MB);
  bf16* Wkb = (bf16*)(ws + 2 * MB);
  bf16* Wvb = (bf16*)(ws + 4 * MB);
  bf16* Wab = (bf16*)(ws + 6 * MB);
  bf16* qb  = (bf16*)(ws + 8 * MB);
  bf16* kb  = (bf16*)(ws + 24 * MB);
  bf16* vb  = (bf16*)(ws + 40 * MB);
  bf16* qp  = (bf16*)(ws + 56 * MB);
  bf16* kp  = (bf16*)(ws + 72 * MB);
  bf16* vp  = (bf16*)(ws + 88 * MB);
  float* part  = (float*)(ws + 104 * MB);             // [16][8192] f32 = 512 KB
  float* alpha = (float*)(ws + 104 * MB + 524288);    // [8][1024]
  bf16* xb  = qb;                       // qb dead after Q projection
  float* xf = (float*)(ws + 24 * MB);   // kb+vb dead after K/V projections

  // out zeroing up front (pool accumulates via atomicAdd)
  hipMemsetAsync(out, 0, 8192 * sizeof(float), stream);

  // all f32 -> bf16 conversions in one dispatch
  CvtAll cv = {{Q, K, V, Wq, Wk, Wv, Wa}, {qb, kb, vb, Wqb, Wkb, Wvb, Wab}};
  f2b_all<<<dim3(4096, 4), 256, 0, stream>>>(cv);

  // projections: one dispatch, y = {q,k,v}; 128 swizzled 256^2 blocks per GEMM
  Gemm3Args g3 = {{{qb, Wqb, bq, qp}, {kb, Wkb, bk, kp}, {vb, Wvb, bv, vp}}};
  gemm3_kernel<<<dim3(128, 3), 512, 0, stream>>>(g3);

  // flash attention
  attn_kernel<<<dim3(128, 16), 256, 0, stream>>>(qp, kp, vp, xb, xf);

  // pooling head partials: 128x256 tiles -> 256 blocks (full chip, 1 round)
  gemm_a_kernel<<<256, 512, 0, stream>>>(xb, Wab, ba, qvec, part);

  // alpha softmax (8 blocks, reads 512KB part) + wide-grid pooling (128 blocks)
  softmax_part<<<8, 256, 0, stream>>>(part, alpha);
  pool_kernel<<<dim3(16, 8), 256, 0, stream>>>(xf, alpha, out);
}